// Round 5
// baseline (211.574 us; speedup 1.0000x reference)
//
#include <hip/hip_runtime.h>
#include <hip/hip_bf16.h>
#include <math.h>

typedef __bf16 bf16x8 __attribute__((ext_vector_type(8)));
typedef float  f32x4  __attribute__((ext_vector_type(4)));

#define M_DIM 16384
#define N_DIM 512
#define K_DIM 512
#define TBL_N 1024     // I_in(V) lerp table over [-4,4]

__device__ inline bf16x8 pack_bf16x8(float4 lo, float4 hi) {
    bf16x8 r;
    r[0] = (__bf16)lo.x; r[1] = (__bf16)lo.y; r[2] = (__bf16)lo.z; r[3] = (__bf16)lo.w;
    r[4] = (__bf16)hi.x; r[5] = (__bf16)hi.y; r[6] = (__bf16)hi.z; r[7] = (__bf16)hi.w;
    return r;
}

// Block tile 128m x 64n, 4 waves in 2x2; wave tile 64m x 32n (mt=4, nt=2).
// NO LDS tiles, NO K-loop barriers: A and B frags load straight from global
// (16 rows x 128B per frag-set = 16 full cache lines, L2-resident via swizzle).
__global__ __launch_bounds__(256, 3)
void snn_fused_kernel(const float* __restrict__ x, const float* __restrict__ W,
                      const float* __restrict__ gNa_p, const float* __restrict__ gK_p,
                      const float* __restrict__ gL_p, float* __restrict__ out)
{
    __shared__ float tbl[TBL_N + 1];

    const int tid = threadIdx.x;

    // ---- exact-HH I_in(V) table (only transcendentals in the kernel) ----
    {
        const float gNa = *gNa_p, gK = *gK_p, gL = *gL_p;
        for (int i = tid; i <= TBL_N; i += 256) {
            const float V = -4.0f + (8.0f / TBL_N) * i;
            const float am = 0.1f * (V + 40.0f) / (1.0f - expf(-(V + 40.0f) * 0.1f));
            const float bm = 4.0f * expf(-(V + 65.0f) * (1.0f / 18.0f));
            const float ah = 0.07f * expf(-(V + 65.0f) * 0.05f);
            const float bh = 1.0f / (1.0f + expf(-(V + 35.0f) * 0.1f));
            const float an = 0.01f * (V + 55.0f) / (1.0f - expf(-(V + 55.0f) * 0.1f));
            const float bn = 0.125f * expf(-(V + 65.0f) * 0.0125f);
            const float m = 0.05f + 0.1f * (am * 0.95f - bm * 0.05f);
            const float h = 0.60f + 0.1f * (ah * 0.40f - bh * 0.60f);
            const float n = 0.32f + 0.1f * (an * 0.68f - bn * 0.32f);
            const float I_ion = gNa * m * m * m * h * (V - 50.0f)
                              + gK * (n * n) * (n * n) * (V + 77.0f)
                              + gL * (V + 54.4f);
            tbl[i] = I_ion + V;
        }
    }
    __syncthreads();   // the ONLY barrier in the kernel

    // ---- XCD swizzle: xcd owns a 16-tile bm band (4 MB of x = its L2);
    // consecutive slots sweep all 8 bn for one bm -> x L2-hot after first pass.
    const int id   = blockIdx.x;        // 0..1023
    const int xcd  = id & 7;
    const int slot = id >> 3;           // 0..127
    const int bm   = xcd * 16 + (slot >> 3);   // 0..127
    const int bn   = slot & 7;                 // 0..7

    const int wave  = tid >> 6;
    const int lane  = tid & 63;
    const int lr    = lane & 15;
    const int quad  = lane >> 4;
    const int mhalf = (wave & 1) * 64;
    const int nhalf = (wave >> 1) * 32;

    const long gmBase = (long)bm * 128 + mhalf;   // wave's first A row
    const int  gnBase = bn * 64 + nhalf;          // wave's first B row

    // per-fragment base pointers: A row gm+mt*16+lr, k-offset quad*8 floats;
    // all 16 K-steps then use immediate offsets (s*128 B, max 1936+16 < 4096).
    const float* aB0 = x + (gmBase +  0 + lr) * (long)K_DIM + quad * 8;
    const float* aB1 = x + (gmBase + 16 + lr) * (long)K_DIM + quad * 8;
    const float* aB2 = x + (gmBase + 32 + lr) * (long)K_DIM + quad * 8;
    const float* aB3 = x + (gmBase + 48 + lr) * (long)K_DIM + quad * 8;
    const float* bB0 = W + (gnBase +  0 + lr) * (long)K_DIM + quad * 8;
    const float* bB1 = W + (gnBase + 16 + lr) * (long)K_DIM + quad * 8;

    f32x4 acc[4][2] = {};

    #pragma unroll
    for (int s = 0; s < 16; ++s) {
        const int off = s * 32;   // floats
        bf16x8 af[4], bfr[2];
        af[0] = pack_bf16x8(*(const float4*)(aB0 + off), *(const float4*)(aB0 + off + 4));
        af[1] = pack_bf16x8(*(const float4*)(aB1 + off), *(const float4*)(aB1 + off + 4));
        af[2] = pack_bf16x8(*(const float4*)(aB2 + off), *(const float4*)(aB2 + off + 4));
        af[3] = pack_bf16x8(*(const float4*)(aB3 + off), *(const float4*)(aB3 + off + 4));
        bfr[0] = pack_bf16x8(*(const float4*)(bB0 + off), *(const float4*)(bB0 + off + 4));
        bfr[1] = pack_bf16x8(*(const float4*)(bB1 + off), *(const float4*)(bB1 + off + 4));
        #pragma unroll
        for (int mt = 0; mt < 4; ++mt)
            #pragma unroll
            for (int nt = 0; nt < 2; ++nt)
                acc[mt][nt] = __builtin_amdgcn_mfma_f32_16x16x32_bf16(
                    af[mt], bfr[nt], acc[mt][nt], 0, 0, 0);
    }

    // ---- table-lerp epilogue, all 3 planes stored in-kernel ----
    float* outS = out;
    float* outV = out + (long)M_DIM * N_DIM;
    float* outW = out + 2L * M_DIM * N_DIM;

    #pragma unroll
    for (int mt = 0; mt < 4; ++mt) {
        #pragma unroll
        for (int i = 0; i < 4; ++i) {
            const long gm = gmBase + mt * 16 + quad * 4 + i;
            #pragma unroll
            for (int nt = 0; nt < 2; ++nt) {
                const int gn = gnBase + nt * 16 + lr;
                const float V = acc[mt][nt][i];

                float u = (V + 4.0f) * (TBL_N / 8.0f);
                u = fminf(fmaxf(u, 0.0f), (float)TBL_N - 0.001f);
                const int   iu = (int)u;
                const float f  = u - (float)iu;
                const float t0 = tbl[iu];
                const float t1 = tbl[iu + 1];
                const float I_in = t0 + f * (t1 - t0);

                const float v_new = -65.0f + I_in * 0.005f;
                const float spike = (v_new >= -50.0f) ? 1.0f : 0.0f;
                const float w_new = (0.5f * (v_new + 65.0f) + 0.1f * spike) * 0.001f;
                const float v_rs  = (spike > 0.5f) ? -65.0f : v_new;

                const long idx = gm * N_DIM + gn;
                outS[idx] = spike;
                outV[idx] = v_rs;
                outW[idx] = w_new;
            }
        }
    }
}

extern "C" void kernel_launch(void* const* d_in, const int* in_sizes, int n_in,
                              void* d_out, int out_size, void* d_ws, size_t ws_size,
                              hipStream_t stream) {
    const float* x   = (const float*)d_in[0];
    const float* W   = (const float*)d_in[1];
    const float* gNa = (const float*)d_in[2];
    const float* gK  = (const float*)d_in[3];
    const float* gL  = (const float*)d_in[4];
    float* out = (float*)d_out;

    dim3 grid((M_DIM / 128) * (N_DIM / 64));   // 1024 blocks
    dim3 block(256);
    hipLaunchKernelGGL(snn_fused_kernel, grid, block, 0, stream, x, W, gNa, gK, gL, out);
}

// Round 6
// 156.472 us; speedup vs baseline: 1.3522x; 1.3522x over previous
//
#include <hip/hip_runtime.h>
#include <hip/hip_bf16.h>
#include <math.h>

typedef __bf16 bf16x4 __attribute__((ext_vector_type(4)));
typedef __bf16 bf16x8 __attribute__((ext_vector_type(8)));
typedef float  f32x4  __attribute__((ext_vector_type(4)));

#define BM 64
#define BN 128
#define BK 64
#define LDST 72        // LDS row stride in bf16 elems (BK + 8 pad)
#define TBL_N 1024     // I_in(V) lerp table over [-4,4]

#define M_DIM 16384
#define N_DIM 512
#define K_DIM 512

__global__ __launch_bounds__(256, 4)
void snn_fused_kernel(const float* __restrict__ x, const float* __restrict__ W,
                      const float* __restrict__ gNa_p, const float* __restrict__ gK_p,
                      const float* __restrict__ gL_p, float* __restrict__ out)
{
    __shared__ __bf16 sA[BM * LDST];
    __shared__ __bf16 sB[BN * LDST];
    __shared__ float  tbl[TBL_N + 1];

    const int tid = threadIdx.x;

    // XCD swizzle: each XCD owns a 32-tile bm band (4 MB of x = its L2)
    const int id   = blockIdx.x;            // 0..1023
    const int xcd  = id & 7;
    const int slot = id >> 3;               // 0..127
    const int bm   = xcd * 32 + (slot >> 2);
    const int bn   = slot & 3;

    const int c4 = (tid & 15) * 4;
    const int r0 = tid >> 4;

    const float* xBase = x + (long)(bm * BM + r0) * K_DIM + c4;
    const float* wBase = W + (long)(bn * BN + r0) * K_DIM + c4;

    const int wave = tid >> 6;
    const int lane = tid & 63;
    const int wM   = (wave & 1) * 32;
    const int wN   = (wave >> 1) * 64;
    const int lr   = lane & 15;
    const int quad = lane >> 4;

    f32x4 acc[2][4] = {};

    // issue first-tile prefetch before the (VALU-heavy) table build so the
    // loads are in flight underneath it
    float4 pa[4], pb[8];
    #pragma unroll
    for (int rr = 0; rr < 4; ++rr)
        pa[rr] = *(const float4*)(xBase + (long)rr * 16 * K_DIM);
    #pragma unroll
    for (int rr = 0; rr < 8; ++rr)
        pb[rr] = *(const float4*)(wBase + (long)rr * 16 * K_DIM);

    // ---- exact-HH I_in(V) table (the only transcendentals in the kernel) ----
    {
        const float gNa = *gNa_p, gK = *gK_p, gL = *gL_p;
        for (int i = tid; i <= TBL_N; i += 256) {
            const float V = -4.0f + (8.0f / TBL_N) * i;
            const float am = 0.1f * (V + 40.0f) / (1.0f - expf(-(V + 40.0f) * 0.1f));
            const float bm_ = 4.0f * expf(-(V + 65.0f) * (1.0f / 18.0f));
            const float ah = 0.07f * expf(-(V + 65.0f) * 0.05f);
            const float bh = 1.0f / (1.0f + expf(-(V + 35.0f) * 0.1f));
            const float an = 0.01f * (V + 55.0f) / (1.0f - expf(-(V + 55.0f) * 0.1f));
            const float bn_ = 0.125f * expf(-(V + 65.0f) * 0.0125f);
            const float m = 0.05f + 0.1f * (am * 0.95f - bm_ * 0.05f);
            const float h = 0.60f + 0.1f * (ah * 0.40f - bh * 0.60f);
            const float n = 0.32f + 0.1f * (an * 0.68f - bn_ * 0.32f);
            const float I_ion = gNa * m * m * m * h * (V - 50.0f)
                              + gK * (n * n) * (n * n) * (V + 77.0f)
                              + gL * (V + 54.4f);
            tbl[i] = I_ion + V;   // I_in
        }
    }

    for (int kt = 0; kt < K_DIM; kt += BK) {
        const int ktn = (kt + BK < K_DIM) ? kt + BK : kt;
        const float* xp = xBase + ktn;
        const float* wp = wBase + ktn;

        #pragma unroll
        for (int rr = 0; rr < 4; ++rr) {
            float4 v = pa[rr];
            pa[rr] = *(const float4*)(xp + (long)rr * 16 * K_DIM);
            bf16x4 b = { (__bf16)v.x, (__bf16)v.y, (__bf16)v.z, (__bf16)v.w };
            *(bf16x4*)(&sA[(r0 + rr * 16) * LDST + c4]) = b;
        }
        #pragma unroll
        for (int rr = 0; rr < 8; ++rr) {
            float4 v = pb[rr];
            pb[rr] = *(const float4*)(wp + (long)rr * 16 * K_DIM);
            bf16x4 b = { (__bf16)v.x, (__bf16)v.y, (__bf16)v.z, (__bf16)v.w };
            *(bf16x4*)(&sB[(r0 + rr * 16) * LDST + c4]) = b;
        }
        __syncthreads();

        #pragma unroll
        for (int ks = 0; ks < BK; ks += 32) {
            bf16x8 af[2], bfr[4];
            #pragma unroll
            for (int t = 0; t < 2; ++t)
                af[t]  = *(const bf16x8*)(&sA[(wM + t * 16 + lr) * LDST + ks + quad * 8]);
            #pragma unroll
            for (int t = 0; t < 4; ++t)
                bfr[t] = *(const bf16x8*)(&sB[(wN + t * 16 + lr) * LDST + ks + quad * 8]);
            #pragma unroll
            for (int mt = 0; mt < 2; ++mt)
                #pragma unroll
                for (int nt = 0; nt < 4; ++nt)
                    acc[mt][nt] = __builtin_amdgcn_mfma_f32_16x16x32_bf16(
                        af[mt], bfr[nt], acc[mt][nt], 0, 0, 0);
        }
        __syncthreads();
    }

    // ---- table-lerp epilogue, all 3 planes stored in-kernel ----
    float* outS = out;
    float* outV = out + (long)M_DIM * N_DIM;
    float* outW = out + 2L * M_DIM * N_DIM;

    #pragma unroll
    for (int mt = 0; mt < 2; ++mt) {
        #pragma unroll
        for (int i = 0; i < 4; ++i) {
            const long gm = (long)bm * BM + wM + mt * 16 + quad * 4 + i;
            #pragma unroll
            for (int nt = 0; nt < 4; ++nt) {
                const int gn = bn * BN + wN + nt * 16 + lr;
                const float V = acc[mt][nt][i];

                float u = (V + 4.0f) * (TBL_N / 8.0f);
                u = fminf(fmaxf(u, 0.0f), (float)TBL_N - 0.001f);
                const int   iu = (int)u;
                const float f  = u - (float)iu;
                const float t0 = tbl[iu];
                const float t1 = tbl[iu + 1];
                const float I_in = t0 + f * (t1 - t0);

                const float v_new = -65.0f + I_in * 0.005f;
                const float spike = (v_new >= -50.0f) ? 1.0f : 0.0f;
                const float w_new = (0.5f * (v_new + 65.0f) + 0.1f * spike) * 0.001f;
                const float v_rs  = (spike > 0.5f) ? -65.0f : v_new;

                const long idx = gm * N_DIM + gn;
                outS[idx] = spike;
                outV[idx] = v_rs;
                outW[idx] = w_new;
            }
        }
    }
}

extern "C" void kernel_launch(void* const* d_in, const int* in_sizes, int n_in,
                              void* d_out, int out_size, void* d_ws, size_t ws_size,
                              hipStream_t stream) {
    const float* x   = (const float*)d_in[0];
    const float* W   = (const float*)d_in[1];
    const float* gNa = (const float*)d_in[2];
    const float* gK  = (const float*)d_in[3];
    const float* gL  = (const float*)d_in[4];
    float* out = (float*)d_out;

    dim3 grid((M_DIM / BM) * (N_DIM / BN));  // 1024 blocks = 4/CU
    dim3 block(256);
    hipLaunchKernelGGL(snn_fused_kernel, grid, block, 0, stream, x, W, gNa, gK, gL, out);
}